// Round 6
// baseline (312.798 us; speedup 1.0000x reference)
//
#include <hip/hip_runtime.h>
#include <hip/hip_fp16.h>

// ---------------- degree / CSR build ----------------

__global__ void zero_ints(int* __restrict__ a, int* __restrict__ b, int n) {
    int i = blockIdx.x * blockDim.x + threadIdx.x;
    if (i < n) { a[i] = 0; b[i] = 0; }
}

__global__ void count_dst(const int* __restrict__ dst, int E, int* __restrict__ cnt) {
    int e = blockIdx.x * blockDim.x + threadIdx.x;
    if (e < E) atomicAdd(&cnt[dst[e]], 1);
}

__global__ void compute_dis(const int* __restrict__ cnt, float* __restrict__ dis, int n) {
    int i = blockIdx.x * blockDim.x + threadIdx.x;
    if (i < n) dis[i] = rsqrtf((float)(cnt[i] + 1));  // +1 self-loop
}

// block scans 1024 elements (256 thr x 4); writes local-exclusive scan + block total
__global__ __launch_bounds__(256) void scanA(const int* __restrict__ cnt,
                                             int* __restrict__ row_ptr,
                                             int* __restrict__ blockSums, int n) {
    __shared__ int s[256];
    int t = threadIdx.x;
    int base = blockIdx.x * 1024 + t * 4;
    int v0 = (base + 0 < n) ? cnt[base + 0] : 0;
    int v1 = (base + 1 < n) ? cnt[base + 1] : 0;
    int v2 = (base + 2 < n) ? cnt[base + 2] : 0;
    int v3 = (base + 3 < n) ? cnt[base + 3] : 0;
    int tsum = v0 + v1 + v2 + v3;
    s[t] = tsum;
    __syncthreads();
    for (int off = 1; off < 256; off <<= 1) {
        int u = (t >= off) ? s[t - off] : 0;
        __syncthreads();
        s[t] += u;
        __syncthreads();
    }
    int excl = s[t] - tsum;
    if (base + 0 < n) row_ptr[base + 0] = excl;
    if (base + 1 < n) row_ptr[base + 1] = excl + v0;
    if (base + 2 < n) row_ptr[base + 2] = excl + v0 + v1;
    if (base + 3 < n) row_ptr[base + 3] = excl + v0 + v1 + v2;
    if (t == 255) blockSums[blockIdx.x] = s[255];
}

// single wave scans <=64 block sums -> exclusive offsets
__global__ void scanB(const int* __restrict__ blockSums, int* __restrict__ blockOff, int B) {
    int t = threadIdx.x;  // 64 threads
    int v = (t < B) ? blockSums[t] : 0;
    int orig = v;
    for (int off = 1; off < 64; off <<= 1) {
        int u = __shfl_up(v, off, 64);
        if (t >= off) v += u;
    }
    if (t < B) blockOff[t] = v - orig;
}

__global__ __launch_bounds__(256) void scanC(int* __restrict__ row_ptr,
                                             const int* __restrict__ blockOff, int n, int E) {
    int base = blockIdx.x * 1024 + threadIdx.x * 4;
    int off = blockOff[blockIdx.x];
    #pragma unroll
    for (int j = 0; j < 4; ++j)
        if (base + j < n) row_ptr[base + j] += off;
    if (blockIdx.x == 0 && threadIdx.x == 0) row_ptr[n] = E;
}

// dst-range-partitioned CSR fill: slot = blockIdx&7 (one XCD per slot under
// round-robin dispatch) owns dst in [slot*n/8,(slot+1)*n/8) -> edge-array lines
// are written from a single XCD, killing the 8x cross-XCD writeback blowup.
__global__ __launch_bounds__(256) void fill_csr_part(const int* __restrict__ src,
                                                     const int* __restrict__ dst, int E, int n,
                                                     const int* __restrict__ row_ptr,
                                                     int* __restrict__ fillc,
                                                     const float* __restrict__ dis,
                                                     int2* __restrict__ edges, int nsub) {
    int slot = blockIdx.x & 7;
    int sub = blockIdx.x >> 3;
    int lo = (int)(((long long)slot * n) >> 3);
    int hi = (int)(((long long)(slot + 1) * n) >> 3);
    int stride = nsub * 256;
    for (int e = sub * 256 + threadIdx.x; e < E; e += stride) {
        int d = dst[e];
        if (d < lo || d >= hi) continue;
        int s = src[e];
        int ofs = atomicAdd(&fillc[d], 1);
        int slotIdx = row_ptr[d] + ofs;
        edges[slotIdx] = make_int2(s, __float_as_int(dis[s] * dis[d]));
    }
}

// ---------------- GEMM: Y[M,N](fp16) = X[M,128](f32) @ W[128,N](f32) ----------------

template <int N>
__global__ __launch_bounds__(256) void gemm_k128(const float* __restrict__ X,
                                                 const float* __restrict__ W,
                                                 __half* __restrict__ Y, int M) {
    constexpr int CG = N / 4;
    constexpr int RG = 256 / CG;
    constexpr int RPT = 64 / RG;
    __shared__ float Xs[64 * 128];    // 32 KB
    int t = threadIdx.x;
    int m0 = blockIdx.x * 64;
    for (int j = t * 4; j < 64 * 128; j += 1024) {
        int row = m0 + (j >> 7);
        float4 v = (row < M) ? *(const float4*)&X[(size_t)row * 128 + (j & 127)]
                             : float4{0.f, 0.f, 0.f, 0.f};
        *(float4*)&Xs[j] = v;
    }
    __syncthreads();
    int mc = t % CG;
    int mr = t / CG;
    float acc[RPT][4] = {};
    const float* xbase = &Xs[(mr * RPT) * 128];
    const float* wp = W + mc * 4;
    #pragma unroll 4
    for (int k = 0; k < 128; ++k) {
        float4 w = *(const float4*)&wp[k * N];
        #pragma unroll
        for (int r = 0; r < RPT; ++r) {
            float xv = xbase[r * 128 + k];
            acc[r][0] += xv * w.x;
            acc[r][1] += xv * w.y;
            acc[r][2] += xv * w.z;
            acc[r][3] += xv * w.w;
        }
    }
    #pragma unroll
    for (int r = 0; r < RPT; ++r) {
        int row = m0 + mr * RPT + r;
        if (row < M) {
            union { __half2 h[2]; float2 f; } u;
            u.h[0] = __floats2half2_rn(acc[r][0], acc[r][1]);
            u.h[1] = __floats2half2_rn(acc[r][2], acc[r][3]);
            *(float2*)&Y[(size_t)row * N + mc * 4] = u.f;
        }
    }
}

// ---------------- aggregation D=128: wave per node, lane = half2(2 dims) ----------------

__global__ __launch_bounds__(256) void agg_gcn128(const __half2* __restrict__ hp,
                                                  const int* __restrict__ row_ptr,
                                                  const int2* __restrict__ edges,
                                                  const float* __restrict__ dis,
                                                  const float* __restrict__ bias,
                                                  float* __restrict__ out, int n) {
    int wid = (blockIdx.x * 256 + threadIdx.x) >> 6;
    if (wid >= n) return;
    int lane = threadIdx.x & 63;
    int beg = row_ptr[wid], end = row_ptr[wid + 1];
    float di = dis[wid];
    float cs = di * di;
    float2 sv = __half22float2(hp[(size_t)wid * 64 + lane]);
    float2 a0 = {cs * sv.x, cs * sv.y};
    float2 a1 = {0.f, 0.f}, a2 = {0.f, 0.f}, a3 = {0.f, 0.f};
    int e = beg;
    for (; e + 4 <= end; e += 4) {
        int2 e0 = edges[e], e1 = edges[e + 1], e2 = edges[e + 2], e3 = edges[e + 3];
        float2 u0 = __half22float2(hp[(size_t)e0.x * 64 + lane]);
        float2 u1 = __half22float2(hp[(size_t)e1.x * 64 + lane]);
        float2 u2 = __half22float2(hp[(size_t)e2.x * 64 + lane]);
        float2 u3 = __half22float2(hp[(size_t)e3.x * 64 + lane]);
        float c0 = __int_as_float(e0.y), c1 = __int_as_float(e1.y);
        float c2 = __int_as_float(e2.y), c3 = __int_as_float(e3.y);
        a0.x += c0 * u0.x; a0.y += c0 * u0.y;
        a1.x += c1 * u1.x; a1.y += c1 * u1.y;
        a2.x += c2 * u2.x; a2.y += c2 * u2.y;
        a3.x += c3 * u3.x; a3.y += c3 * u3.y;
    }
    for (; e < end; ++e) {
        int2 e0 = edges[e];
        float c0 = __int_as_float(e0.y);
        float2 u0 = __half22float2(hp[(size_t)e0.x * 64 + lane]);
        a0.x += c0 * u0.x; a0.y += c0 * u0.y;
    }
    float2 bv = ((const float2*)bias)[lane];
    float2 o;
    o.x = fmaxf(a0.x + a1.x + a2.x + a3.x + bv.x, 0.f);
    o.y = fmaxf(a0.y + a1.y + a2.y + a3.y + bv.y, 0.f);
    ((float2*)out)[(size_t)wid * 64 + lane] = o;
}

// ---------------- aggregation D=64: 2 nodes per wave (32 lanes x half2) ----------------

__global__ __launch_bounds__(256) void agg_gcn64(const __half2* __restrict__ hp,
                                                 const int* __restrict__ row_ptr,
                                                 const int2* __restrict__ edges,
                                                 const float* __restrict__ dis,
                                                 const float* __restrict__ bias,
                                                 float* __restrict__ out, int n) {
    int node = (blockIdx.x * 256 + threadIdx.x) >> 5;
    if (node >= n) return;
    int l = threadIdx.x & 31;
    int beg = row_ptr[node], end = row_ptr[node + 1];
    float di = dis[node];
    float cs = di * di;
    float2 sv = __half22float2(hp[(size_t)node * 32 + l]);
    float2 a0 = {cs * sv.x, cs * sv.y};
    float2 a1 = {0.f, 0.f};
    int e = beg;
    for (; e + 2 <= end; e += 2) {
        int2 e0 = edges[e], e1 = edges[e + 1];
        float2 u0 = __half22float2(hp[(size_t)e0.x * 32 + l]);
        float2 u1 = __half22float2(hp[(size_t)e1.x * 32 + l]);
        float c0 = __int_as_float(e0.y), c1 = __int_as_float(e1.y);
        a0.x += c0 * u0.x; a0.y += c0 * u0.y;
        a1.x += c1 * u1.x; a1.y += c1 * u1.y;
    }
    if (e < end) {
        int2 e0 = edges[e];
        float c0 = __int_as_float(e0.y);
        float2 u0 = __half22float2(hp[(size_t)e0.x * 32 + l]);
        a0.x += c0 * u0.x; a0.y += c0 * u0.y;
    }
    float2 bv = ((const float2*)bias)[l];
    float2 o;
    o.x = fmaxf(a0.x + a1.x + bv.x, 0.f);
    o.y = fmaxf(a0.y + a1.y + bv.y, 0.f);
    ((float2*)out)[(size_t)node * 32 + l] = o;
}

// ---------------- projection + relu + row-normalize: register-blocked GEMM ----------------

__global__ __launch_bounds__(256) void proj_norm2(const float* __restrict__ O,
                                                  const float* __restrict__ Wp,
                                                  float* __restrict__ P, int n) {
    __shared__ float oT[64 * 68];  // [k][node], stride 68 keeps float4 16B-aligned
    __shared__ float Ws[64 * 64];  // [k][col]
    int t = threadIdx.x;
    int base = blockIdx.x * 64;
    for (int j = t * 4; j < 4096; j += 1024)
        *(float4*)&Ws[j] = *(const float4*)&Wp[j];
    for (int j = t * 4; j < 4096; j += 1024) {
        int row = j >> 6;   // node-in-block
        int col = j & 63;   // k
        int node = base + row;
        float4 v = (node < n) ? *(const float4*)&O[(size_t)node * 64 + col]
                              : float4{0.f, 0.f, 0.f, 0.f};
        oT[(col + 0) * 68 + row] = v.x;
        oT[(col + 1) * 68 + row] = v.y;
        oT[(col + 2) * 68 + row] = v.z;
        oT[(col + 3) * 68 + row] = v.w;
    }
    __syncthreads();
    int cg = t & 15;   // col group (4 cols)
    int ng = t >> 4;   // node group (4 nodes)
    float acc[4][4] = {};
    const float* otp = &oT[ng * 4];
    const float* wsp = &Ws[cg * 4];
    #pragma unroll 2
    for (int k = 0; k < 64; ++k) {
        float4 ov = *(const float4*)&otp[k * 68];
        float4 wv = *(const float4*)&wsp[k * 64];
        #pragma unroll
        for (int i = 0; i < 4; ++i) {
            float o = (&ov.x)[i];
            acc[i][0] += o * wv.x;
            acc[i][1] += o * wv.y;
            acc[i][2] += o * wv.z;
            acc[i][3] += o * wv.w;
        }
    }
    #pragma unroll
    for (int i = 0; i < 4; ++i) {
        float4 p;
        p.x = fmaxf(acc[i][0], 0.f);
        p.y = fmaxf(acc[i][1], 0.f);
        p.z = fmaxf(acc[i][2], 0.f);
        p.w = fmaxf(acc[i][3], 0.f);
        float ss = p.x * p.x + p.y * p.y + p.z * p.z + p.w * p.w;
        #pragma unroll
        for (int off = 1; off < 16; off <<= 1) ss += __shfl_xor(ss, off, 64);
        float norm = sqrtf(ss);
        float sc = 1.0f / fmaxf(norm, 1e-12f);
        int node = base + ng * 4 + i;
        if (node < n) {
            p.x *= sc; p.y *= sc; p.z *= sc; p.w *= sc;
            *(float4*)&P[(size_t)node * 64 + cg * 4] = p;
        }
    }
}

// ---------------- launch ----------------

static inline size_t ws_align(size_t x) { return (x + 255) & ~(size_t)255; }

extern "C" void kernel_launch(void* const* d_in, const int* in_sizes, int n_in,
                              void* d_out, int out_size, void* d_ws, size_t ws_size,
                              hipStream_t stream) {
    const float* x  = (const float*)d_in[0];
    const int*   ei = (const int*)d_in[1];
    const float* W1 = (const float*)d_in[2];
    const float* b1 = (const float*)d_in[3];
    const float* W2 = (const float*)d_in[4];
    const float* b2 = (const float*)d_in[5];
    const float* W3 = (const float*)d_in[6];
    const float* b3 = (const float*)d_in[7];
    const float* Wp = (const float*)d_in[8];

    int n = in_sizes[0] / 128;
    int E = in_sizes[1] / 2;
    const int* src = ei;
    const int* dst = ei + E;

    char* ws = (char*)d_ws;
    size_t off = 0;
    auto alloc = [&](size_t bytes) -> void* {
        void* p = ws + off;
        off = ws_align(off + bytes);
        return p;
    };
    __half* bufH    = (__half*)alloc((size_t)n * 128 * 2);  // fp16 GEMM out (gather operand)
    float*  bufF    = (float*)alloc((size_t)n * 128 * 4);   // f32 agg out (GEMM input)
    int*   cnt      = (int*)alloc((size_t)n * 4);
    int*   fillc    = (int*)alloc((size_t)n * 4);
    float* dis      = (float*)alloc((size_t)n * 4);
    int*   row_ptr  = (int*)alloc((size_t)(n + 1) * 4);
    int2*  edges    = (int2*)alloc((size_t)E * 8);
    int*   blockSums = (int*)alloc(256);
    int*   blockOff  = (int*)alloc(256);
    (void)off; (void)ws_size;

    int B = (n + 1023) / 1024;
    zero_ints<<<(n + 255) / 256, 256, 0, stream>>>(cnt, fillc, n);
    count_dst<<<(E + 255) / 256, 256, 0, stream>>>(dst, E, cnt);
    compute_dis<<<(n + 255) / 256, 256, 0, stream>>>(cnt, dis, n);
    scanA<<<B, 256, 0, stream>>>(cnt, row_ptr, blockSums, n);
    scanB<<<1, 64, 0, stream>>>(blockSums, blockOff, B);
    scanC<<<B, 256, 0, stream>>>(row_ptr, blockOff, n, E);
    int nsub = 56;
    fill_csr_part<<<nsub * 8, 256, 0, stream>>>(src, dst, E, n, row_ptr, fillc, dis, edges, nsub);

    int gblocks = (n + 63) / 64;
    int ablocks = (n + 3) / 4;       // wave-per-node kernels (4 nodes/block)
    int a64blocks = (n + 7) / 8;     // 2 nodes/wave (8 nodes/block)
    int pblocks = (n + 63) / 64;
    float* outp = (float*)d_out;

    gemm_k128<128><<<gblocks, 256, 0, stream>>>(x, W1, bufH, n);
    agg_gcn128<<<ablocks, 256, 0, stream>>>((const __half2*)bufH, row_ptr, edges, dis, b1, bufF, n);
    gemm_k128<128><<<gblocks, 256, 0, stream>>>(bufF, W2, bufH, n);
    agg_gcn128<<<ablocks, 256, 0, stream>>>((const __half2*)bufH, row_ptr, edges, dis, b2, bufF, n);
    gemm_k128<64><<<gblocks, 256, 0, stream>>>(bufF, W3, bufH, n);
    agg_gcn64<<<a64blocks, 256, 0, stream>>>((const __half2*)bufH, row_ptr, edges, dis, b3, bufF, n);
    proj_norm2<<<pblocks, 256, 0, stream>>>(bufF, Wp, outp, n);
}

// Round 7
// 296.764 us; speedup vs baseline: 1.0540x; 1.0540x over previous
//
#include <hip/hip_runtime.h>
#include <hip/hip_fp16.h>

// ---------------- degree / CSR build ----------------

__global__ void zero_ints(int* __restrict__ a, int* __restrict__ b, int n) {
    int i = blockIdx.x * blockDim.x + threadIdx.x;
    if (i < n) { a[i] = 0; b[i] = 0; }
}

__global__ void count_dst(const int* __restrict__ dst, int E, int* __restrict__ cnt) {
    int e = blockIdx.x * blockDim.x + threadIdx.x;
    if (e < E) atomicAdd(&cnt[dst[e]], 1);
}

__global__ void compute_dis(const int* __restrict__ cnt, float* __restrict__ dis, int n) {
    int i = blockIdx.x * blockDim.x + threadIdx.x;
    if (i < n) dis[i] = rsqrtf((float)(cnt[i] + 1));  // +1 self-loop
}

// block scans 1024 elements (256 thr x 4); writes local-exclusive scan + block total
__global__ __launch_bounds__(256) void scanA(const int* __restrict__ cnt,
                                             int* __restrict__ row_ptr,
                                             int* __restrict__ blockSums, int n) {
    __shared__ int s[256];
    int t = threadIdx.x;
    int base = blockIdx.x * 1024 + t * 4;
    int v0 = (base + 0 < n) ? cnt[base + 0] : 0;
    int v1 = (base + 1 < n) ? cnt[base + 1] : 0;
    int v2 = (base + 2 < n) ? cnt[base + 2] : 0;
    int v3 = (base + 3 < n) ? cnt[base + 3] : 0;
    int tsum = v0 + v1 + v2 + v3;
    s[t] = tsum;
    __syncthreads();
    for (int off = 1; off < 256; off <<= 1) {
        int u = (t >= off) ? s[t - off] : 0;
        __syncthreads();
        s[t] += u;
        __syncthreads();
    }
    int excl = s[t] - tsum;
    if (base + 0 < n) row_ptr[base + 0] = excl;
    if (base + 1 < n) row_ptr[base + 1] = excl + v0;
    if (base + 2 < n) row_ptr[base + 2] = excl + v0 + v1;
    if (base + 3 < n) row_ptr[base + 3] = excl + v0 + v1 + v2;
    if (t == 255) blockSums[blockIdx.x] = s[255];
}

// single wave scans <=64 block sums -> exclusive offsets
__global__ void scanB(const int* __restrict__ blockSums, int* __restrict__ blockOff, int B) {
    int t = threadIdx.x;  // 64 threads
    int v = (t < B) ? blockSums[t] : 0;
    int orig = v;
    for (int off = 1; off < 64; off <<= 1) {
        int u = __shfl_up(v, off, 64);
        if (t >= off) v += u;
    }
    if (t < B) blockOff[t] = v - orig;
}

__global__ __launch_bounds__(256) void scanC(int* __restrict__ row_ptr,
                                             const int* __restrict__ blockOff, int n, int E) {
    int base = blockIdx.x * 1024 + threadIdx.x * 4;
    int off = blockOff[blockIdx.x];
    #pragma unroll
    for (int j = 0; j < 4; ++j)
        if (base + j < n) row_ptr[base + j] += off;
    if (blockIdx.x == 0 && threadIdx.x == 0) row_ptr[n] = E;
}

// edges[slot] = packed { u16 src, fp16 coef } — 4B scattered store per edge
__global__ void fill_csr(const int* __restrict__ src, const int* __restrict__ dst, int E,
                         const int* __restrict__ row_ptr, int* __restrict__ fillc,
                         const float* __restrict__ dis,
                         unsigned int* __restrict__ edges) {
    int e = blockIdx.x * blockDim.x + threadIdx.x;
    if (e >= E) return;
    int d = dst[e], s = src[e];
    int ofs = atomicAdd(&fillc[d], 1);
    int slot = row_ptr[d] + ofs;
    float coef = dis[s] * dis[d];
    unsigned int packed = (unsigned int)s |
                          ((unsigned int)__half_as_ushort(__float2half_rn(coef)) << 16);
    edges[slot] = packed;
}

__device__ __forceinline__ void unpack_edge(unsigned int w, int& s, float& c) {
    s = (int)(w & 0xffffu);
    c = __half2float(__ushort_as_half((unsigned short)(w >> 16)));
}

// ---------------- GEMM: Y[M,N](fp16) = X[M,128](f32) @ W[128,N](f32) ----------------

template <int N>
__global__ __launch_bounds__(256) void gemm_k128(const float* __restrict__ X,
                                                 const float* __restrict__ W,
                                                 __half* __restrict__ Y, int M) {
    constexpr int CG = N / 4;
    constexpr int RG = 256 / CG;
    constexpr int RPT = 64 / RG;
    __shared__ float Xs[64 * 128];    // 32 KB
    int t = threadIdx.x;
    int m0 = blockIdx.x * 64;
    for (int j = t * 4; j < 64 * 128; j += 1024) {
        int row = m0 + (j >> 7);
        float4 v = (row < M) ? *(const float4*)&X[(size_t)row * 128 + (j & 127)]
                             : float4{0.f, 0.f, 0.f, 0.f};
        *(float4*)&Xs[j] = v;
    }
    __syncthreads();
    int mc = t % CG;
    int mr = t / CG;
    float acc[RPT][4] = {};
    const float* xbase = &Xs[(mr * RPT) * 128];
    const float* wp = W + mc * 4;
    #pragma unroll 4
    for (int k = 0; k < 128; ++k) {
        float4 w = *(const float4*)&wp[k * N];
        #pragma unroll
        for (int r = 0; r < RPT; ++r) {
            float xv = xbase[r * 128 + k];
            acc[r][0] += xv * w.x;
            acc[r][1] += xv * w.y;
            acc[r][2] += xv * w.z;
            acc[r][3] += xv * w.w;
        }
    }
    #pragma unroll
    for (int r = 0; r < RPT; ++r) {
        int row = m0 + mr * RPT + r;
        if (row < M) {
            union { __half2 h[2]; float2 f; } u;
            u.h[0] = __floats2half2_rn(acc[r][0], acc[r][1]);
            u.h[1] = __floats2half2_rn(acc[r][2], acc[r][3]);
            *(float2*)&Y[(size_t)row * N + mc * 4] = u.f;
        }
    }
}

// ---------------- aggregation D=128: wave per node, lane = half2(2 dims) ----------------

__global__ __launch_bounds__(256) void agg_gcn128(const __half2* __restrict__ hp,
                                                  const int* __restrict__ row_ptr,
                                                  const unsigned int* __restrict__ edges,
                                                  const float* __restrict__ dis,
                                                  const float* __restrict__ bias,
                                                  float* __restrict__ out, int n) {
    int wid = (blockIdx.x * 256 + threadIdx.x) >> 6;
    if (wid >= n) return;
    int lane = threadIdx.x & 63;
    int beg = row_ptr[wid], end = row_ptr[wid + 1];
    float di = dis[wid];
    float cs = di * di;
    float2 sv = __half22float2(hp[(size_t)wid * 64 + lane]);
    float2 a0 = {cs * sv.x, cs * sv.y};
    float2 a1 = {0.f, 0.f}, a2 = {0.f, 0.f}, a3 = {0.f, 0.f};
    int e = beg;
    for (; e + 4 <= end; e += 4) {
        unsigned int w0 = edges[e], w1 = edges[e + 1], w2 = edges[e + 2], w3 = edges[e + 3];
        int s0, s1, s2, s3; float c0, c1, c2, c3;
        unpack_edge(w0, s0, c0); unpack_edge(w1, s1, c1);
        unpack_edge(w2, s2, c2); unpack_edge(w3, s3, c3);
        float2 u0 = __half22float2(hp[(size_t)s0 * 64 + lane]);
        float2 u1 = __half22float2(hp[(size_t)s1 * 64 + lane]);
        float2 u2 = __half22float2(hp[(size_t)s2 * 64 + lane]);
        float2 u3 = __half22float2(hp[(size_t)s3 * 64 + lane]);
        a0.x += c0 * u0.x; a0.y += c0 * u0.y;
        a1.x += c1 * u1.x; a1.y += c1 * u1.y;
        a2.x += c2 * u2.x; a2.y += c2 * u2.y;
        a3.x += c3 * u3.x; a3.y += c3 * u3.y;
    }
    for (; e < end; ++e) {
        int s0; float c0;
        unpack_edge(edges[e], s0, c0);
        float2 u0 = __half22float2(hp[(size_t)s0 * 64 + lane]);
        a0.x += c0 * u0.x; a0.y += c0 * u0.y;
    }
    float2 bv = ((const float2*)bias)[lane];
    float2 o;
    o.x = fmaxf(a0.x + a1.x + a2.x + a3.x + bv.x, 0.f);
    o.y = fmaxf(a0.y + a1.y + a2.y + a3.y + bv.y, 0.f);
    ((float2*)out)[(size_t)wid * 64 + lane] = o;
}

// ---------------- aggregation D=64: 2 nodes per wave (32 lanes x half2) ----------------

__global__ __launch_bounds__(256) void agg_gcn64(const __half2* __restrict__ hp,
                                                 const int* __restrict__ row_ptr,
                                                 const unsigned int* __restrict__ edges,
                                                 const float* __restrict__ dis,
                                                 const float* __restrict__ bias,
                                                 float* __restrict__ out, int n) {
    int node = (blockIdx.x * 256 + threadIdx.x) >> 5;
    if (node >= n) return;
    int l = threadIdx.x & 31;
    int beg = row_ptr[node], end = row_ptr[node + 1];
    float di = dis[node];
    float cs = di * di;
    float2 sv = __half22float2(hp[(size_t)node * 32 + l]);
    float2 a0 = {cs * sv.x, cs * sv.y};
    float2 a1 = {0.f, 0.f};
    int e = beg;
    for (; e + 2 <= end; e += 2) {
        unsigned int w0 = edges[e], w1 = edges[e + 1];
        int s0, s1; float c0, c1;
        unpack_edge(w0, s0, c0); unpack_edge(w1, s1, c1);
        float2 u0 = __half22float2(hp[(size_t)s0 * 32 + l]);
        float2 u1 = __half22float2(hp[(size_t)s1 * 32 + l]);
        a0.x += c0 * u0.x; a0.y += c0 * u0.y;
        a1.x += c1 * u1.x; a1.y += c1 * u1.y;
    }
    if (e < end) {
        int s0; float c0;
        unpack_edge(edges[e], s0, c0);
        float2 u0 = __half22float2(hp[(size_t)s0 * 32 + l]);
        a0.x += c0 * u0.x; a0.y += c0 * u0.y;
    }
    float2 bv = ((const float2*)bias)[l];
    float2 o;
    o.x = fmaxf(a0.x + a1.x + bv.x, 0.f);
    o.y = fmaxf(a0.y + a1.y + bv.y, 0.f);
    ((float2*)out)[(size_t)node * 32 + l] = o;
}

// ---------------- projection + relu + row-normalize: register-blocked GEMM ----------------

__global__ __launch_bounds__(256) void proj_norm2(const float* __restrict__ O,
                                                  const float* __restrict__ Wp,
                                                  float* __restrict__ P, int n) {
    __shared__ float oT[64 * 68];  // [k][node], stride 68 keeps float4 16B-aligned
    __shared__ float Ws[64 * 64];  // [k][col]
    int t = threadIdx.x;
    int base = blockIdx.x * 64;
    for (int j = t * 4; j < 4096; j += 1024)
        *(float4*)&Ws[j] = *(const float4*)&Wp[j];
    for (int j = t * 4; j < 4096; j += 1024) {
        int row = j >> 6;   // node-in-block
        int col = j & 63;   // k
        int node = base + row;
        float4 v = (node < n) ? *(const float4*)&O[(size_t)node * 64 + col]
                              : float4{0.f, 0.f, 0.f, 0.f};
        oT[(col + 0) * 68 + row] = v.x;
        oT[(col + 1) * 68 + row] = v.y;
        oT[(col + 2) * 68 + row] = v.z;
        oT[(col + 3) * 68 + row] = v.w;
    }
    __syncthreads();
    int cg = t & 15;   // col group (4 cols)
    int ng = t >> 4;   // node group (4 nodes)
    float acc[4][4] = {};
    const float* otp = &oT[ng * 4];
    const float* wsp = &Ws[cg * 4];
    #pragma unroll 2
    for (int k = 0; k < 64; ++k) {
        float4 ov = *(const float4*)&otp[k * 68];
        float4 wv = *(const float4*)&wsp[k * 64];
        #pragma unroll
        for (int i = 0; i < 4; ++i) {
            float o = (&ov.x)[i];
            acc[i][0] += o * wv.x;
            acc[i][1] += o * wv.y;
            acc[i][2] += o * wv.z;
            acc[i][3] += o * wv.w;
        }
    }
    #pragma unroll
    for (int i = 0; i < 4; ++i) {
        float4 p;
        p.x = fmaxf(acc[i][0], 0.f);
        p.y = fmaxf(acc[i][1], 0.f);
        p.z = fmaxf(acc[i][2], 0.f);
        p.w = fmaxf(acc[i][3], 0.f);
        float ss = p.x * p.x + p.y * p.y + p.z * p.z + p.w * p.w;
        #pragma unroll
        for (int off = 1; off < 16; off <<= 1) ss += __shfl_xor(ss, off, 64);
        float norm = sqrtf(ss);
        float sc = 1.0f / fmaxf(norm, 1e-12f);
        int node = base + ng * 4 + i;
        if (node < n) {
            p.x *= sc; p.y *= sc; p.z *= sc; p.w *= sc;
            *(float4*)&P[(size_t)node * 64 + cg * 4] = p;
        }
    }
}

// ---------------- launch ----------------

static inline size_t ws_align(size_t x) { return (x + 255) & ~(size_t)255; }

extern "C" void kernel_launch(void* const* d_in, const int* in_sizes, int n_in,
                              void* d_out, int out_size, void* d_ws, size_t ws_size,
                              hipStream_t stream) {
    const float* x  = (const float*)d_in[0];
    const int*   ei = (const int*)d_in[1];
    const float* W1 = (const float*)d_in[2];
    const float* b1 = (const float*)d_in[3];
    const float* W2 = (const float*)d_in[4];
    const float* b2 = (const float*)d_in[5];
    const float* W3 = (const float*)d_in[6];
    const float* b3 = (const float*)d_in[7];
    const float* Wp = (const float*)d_in[8];

    int n = in_sizes[0] / 128;
    int E = in_sizes[1] / 2;
    const int* src = ei;
    const int* dst = ei + E;

    char* ws = (char*)d_ws;
    size_t off = 0;
    auto alloc = [&](size_t bytes) -> void* {
        void* p = ws + off;
        off = ws_align(off + bytes);
        return p;
    };
    __half* bufH    = (__half*)alloc((size_t)n * 128 * 2);  // fp16 GEMM out (gather operand)
    float*  bufF    = (float*)alloc((size_t)n * 128 * 4);   // f32 agg out (GEMM input)
    int*   cnt      = (int*)alloc((size_t)n * 4);
    int*   fillc    = (int*)alloc((size_t)n * 4);
    float* dis      = (float*)alloc((size_t)n * 4);
    int*   row_ptr  = (int*)alloc((size_t)(n + 1) * 4);
    unsigned int* edges = (unsigned int*)alloc((size_t)E * 4);
    int*   blockSums = (int*)alloc(256);
    int*   blockOff  = (int*)alloc(256);
    (void)off; (void)ws_size;

    int B = (n + 1023) / 1024;
    zero_ints<<<(n + 255) / 256, 256, 0, stream>>>(cnt, fillc, n);
    count_dst<<<(E + 255) / 256, 256, 0, stream>>>(dst, E, cnt);
    compute_dis<<<(n + 255) / 256, 256, 0, stream>>>(cnt, dis, n);
    scanA<<<B, 256, 0, stream>>>(cnt, row_ptr, blockSums, n);
    scanB<<<1, 64, 0, stream>>>(blockSums, blockOff, B);
    scanC<<<B, 256, 0, stream>>>(row_ptr, blockOff, n, E);
    fill_csr<<<(E + 255) / 256, 256, 0, stream>>>(src, dst, E, row_ptr, fillc, dis, edges);

    int gblocks = (n + 63) / 64;
    int ablocks = (n + 3) / 4;       // wave-per-node kernels (4 nodes/block)
    int a64blocks = (n + 7) / 8;     // 2 nodes/wave (8 nodes/block)
    int pblocks = (n + 63) / 64;
    float* outp = (float*)d_out;

    gemm_k128<128><<<gblocks, 256, 0, stream>>>(x, W1, bufH, n);
    agg_gcn128<<<ablocks, 256, 0, stream>>>((const __half2*)bufH, row_ptr, edges, dis, b1, bufF, n);
    gemm_k128<128><<<gblocks, 256, 0, stream>>>(bufF, W2, bufH, n);
    agg_gcn128<<<ablocks, 256, 0, stream>>>((const __half2*)bufH, row_ptr, edges, dis, b2, bufF, n);
    gemm_k128<64><<<gblocks, 256, 0, stream>>>(bufF, W3, bufH, n);
    agg_gcn64<<<a64blocks, 256, 0, stream>>>((const __half2*)bufH, row_ptr, edges, dis, b3, bufF, n);
    proj_norm2<<<pblocks, 256, 0, stream>>>(bufF, Wp, outp, n);
}